// Round 2
// baseline (460.299 us; speedup 1.0000x reference)
//
#include <hip/hip_runtime.h>

#define NROWS 8192
#define DIM 512
#define HID 1024
#define BN_EPS 1e-5f

typedef unsigned short ushort_t;
typedef __attribute__((ext_vector_type(8))) __bf16 bf16x8;
typedef __attribute__((ext_vector_type(4))) float f32x4;

union U4 {
    uint4 u;
    bf16x8 b;
    ushort_t s[8];
};

static __device__ __forceinline__ float b2f(ushort_t u) {
    union { float f; unsigned int i; } c;
    c.i = ((unsigned int)u) << 16;
    return c.f;
}

static __device__ __forceinline__ ushort_t f2b(float f) {
    union { float f; unsigned int i; } c;
    c.f = f;
    unsigned int i = c.i;
    unsigned int r = (i + 0x7FFFu + ((i >> 16) & 1u)) >> 16;
    return (ushort_t)r;
}

// async global->LDS, 16B per lane. LDS dest is wave-uniform base + lane*16.
static __device__ __forceinline__ void gload_lds16(const ushort_t* g, ushort_t* l) {
    __builtin_amdgcn_global_load_lds((const __attribute__((address_space(1))) void*)g,
                                     (__attribute__((address_space(3))) void*)l, 16, 0, 0);
}

// ---------------------------------------------------------------------------
// 1) column-sum of h: hs[d] = sum_n h[n,d]   (hs pre-zeroed by memset)
// grid 256 x 256; each block covers 32 rows; LDS pre-reduce halves atomics.
__global__ void colsum_kernel(const float* __restrict__ h, float* __restrict__ hs) {
    __shared__ float red[512];
    int t = threadIdx.x;
    int col0 = (t & 127) * 4;
    int rsub = t >> 7;
    int row0 = blockIdx.x * 32;
    float acc[4] = {0.f, 0.f, 0.f, 0.f};
#pragma unroll
    for (int r = 0; r < 16; ++r) {
        int row = row0 + r * 2 + rsub;
        float4 v = *(const float4*)(h + (size_t)row * DIM + col0);
        acc[0] += v.x; acc[1] += v.y; acc[2] += v.z; acc[3] += v.w;
    }
    if (rsub) {
#pragma unroll
        for (int j = 0; j < 4; ++j) red[col0 + j] = acc[j];
    }
    __syncthreads();
    if (!rsub) {
#pragma unroll
        for (int j = 0; j < 4; ++j) atomicAdd(&hs[col0 + j], acc[j] + red[col0 + j]);
    }
}

// ---------------------------------------------------------------------------
// 2) fused vector chain: s = hs@vw + 8192*vb (full 512, redundant per block),
// then this block's 32 cols of t = s@ow + ob, then BN constants.
// grid 16 x 256.
__global__ void chainprep_kernel(const float* __restrict__ hs,
                                 const float* __restrict__ vw, const float* __restrict__ vb,
                                 const float* __restrict__ ow, const float* __restrict__ ob,
                                 const float* g1, const float* b1,
                                 const float* m1, const float* v1,
                                 const float* g2, const float* b2,
                                 const float* m2, const float* v2,
                                 float* __restrict__ p, float* __restrict__ q0,
                                 float* __restrict__ a2v, float* __restrict__ c2v) {
    __shared__ float sS[512];
    __shared__ float red[8][32];
    int t = threadIdx.x;
    float acc0 = 0.f, acc1 = 0.f;
    for (int k = 0; k < 512; ++k) {
        float hv = hs[k];
        acc0 += hv * vw[k * 512 + t];
        acc1 += hv * vw[k * 512 + t + 256];
    }
    sS[t] = acc0 + 8192.0f * vb[t];
    sS[t + 256] = acc1 + 8192.0f * vb[t + 256];
    __syncthreads();
    int col = blockIdx.x * 32 + (t & 31);
    int ks = t >> 5;
    float s2 = 0.f;
    for (int ki = 0; ki < 64; ++ki) {
        int k = ks * 64 + ki;
        s2 += sS[k] * ow[k * 512 + col];
    }
    red[ks][t & 31] = s2;
    __syncthreads();
    if (ks == 0) {
        float tot = ob[col];
#pragma unroll
        for (int r = 0; r < 8; ++r) tot += red[r][t & 31];
        float a1 = g1[col] * rsqrtf(v1[col] + BN_EPS);
        float c1 = b1[col] - m1[col] * a1;
        p[col] = a1;
        q0[col] = tot * a1 + c1;
        float a2 = g2[col] * rsqrtf(v2[col] + BN_EPS);
        a2v[col] = a2;
        c2v[col] = b2[col] - m2[col] * a2;
    }
}

// ---------------------------------------------------------------------------
// 3) both weight transposes in one launch. blocks 0..511: f1w [512][1024] -> W1T;
// blocks 512..1023: f2w [1024][512] -> W2T.  32x32 tiles, 256 threads.
__global__ void transpose_both_kernel(const float* __restrict__ f1w, ushort_t* __restrict__ W1T,
                                      const float* __restrict__ f2w, ushort_t* __restrict__ W2T) {
    __shared__ float tile[32][33];
    int bid = blockIdx.x;
    const float* in;
    ushort_t* out;
    int R, C, bx, by;
    if (bid < 512) {
        in = f1w; out = W1T; R = 512; C = 1024;
        bx = (bid & 31) * 32; by = (bid >> 5) * 32;
    } else {
        int b = bid - 512;
        in = f2w; out = W2T; R = 1024; C = 512;
        bx = (b & 15) * 32; by = (b >> 4) * 32;
    }
    int tx = threadIdx.x & 31, ty = threadIdx.x >> 5;
#pragma unroll
    for (int i = 0; i < 32; i += 8)
        tile[ty + i][tx] = in[(by + ty + i) * C + bx + tx];
    __syncthreads();
#pragma unroll
    for (int i = 0; i < 32; i += 8)
        out[(bx + ty + i) * R + by + tx] = f2b(tile[tx][ty + i]);
}

// ---------------------------------------------------------------------------
// stage a [ROWS][64] bf16 tile from global (row stride ldg) into linear LDS
// via global_load_lds x16.  8 chunks of 16B per row; chunk c = it*256 + tid.
template <int ROWS>
static __device__ __forceinline__ void stage_tile(const ushort_t* __restrict__ g, int ldg,
                                                  ushort_t* lds, int tid) {
#pragma unroll
    for (int it = 0; it < (ROWS * 8) / 256; ++it) {
        int c = it * 256 + tid;
        int row = c >> 3;
        int kc = (c & 7) << 3;
        const ushort_t* gp = g + (size_t)row * ldg + kc;
        ushort_t* lp = lds + ((it * 256 + (tid & 192)) << 3);  // wave-uniform base
        gload_lds16(gp, lp);
    }
}

// ---------------------------------------------------------------------------
// 4) GEMM, m97 structure: 128 x (NJ*32) tile, BK=64, 4 waves (2x2),
// 16x16x32 bf16 MFMA, 4 x NJ frags per wave.
// AH=true : A-tile computed on the fly from fp32 h: bf16(h*p+q0) (fuses x1).
// FUSE=true: epilogue computes out = ((h*p+q0) + acc + bias)*a2 + c2, fp32.
template <int NJ, bool RELU, bool FUSE, bool AH>
__global__ __launch_bounds__(256) void gemm_kernel(
    const ushort_t* __restrict__ A, const float* __restrict__ Ah,
    const ushort_t* __restrict__ BT,
    const float* __restrict__ bias, ushort_t* __restrict__ Cb,
    float* __restrict__ Cf, int M, int Nn, int K,
    const float* __restrict__ h, const float* __restrict__ p,
    const float* __restrict__ q0, const float* __restrict__ a2,
    const float* __restrict__ c2) {
    constexpr int BN = NJ * 32;
    constexpr int BK = 64;
    __shared__ ushort_t As[128 * BK];
    __shared__ ushort_t Bs[BN * BK];
    int tid = threadIdx.x;
    int lane = tid & 63, w = tid >> 6;
    int wm = (w & 1) * 64, wn = (w >> 1) * (NJ * 16);
    int bm = blockIdx.y * 128, bn = blockIdx.x * BN;

    f32x4 acc[4][NJ] = {};

    const ushort_t* Ag = A + (size_t)bm * K;
    const ushort_t* Bg = BT + (size_t)bn * K;

    for (int k0 = 0; k0 < K; k0 += BK) {
        __syncthreads();
        if constexpr (AH) {
            // A = bf16(h*p + q0) staged through registers (x1 fused in).
#pragma unroll
            for (int it = 0; it < 8; ++it) {
                int c = it * 256 + tid;
                int row = c >> 4, q = (c & 15) * 4;
                float4 hv = *(const float4*)(Ah + (size_t)(bm + row) * K + k0 + q);
                float4 pv = *(const float4*)(p + k0 + q);
                float4 qv = *(const float4*)(q0 + k0 + q);
                ushort_t o[4];
                o[0] = f2b(hv.x * pv.x + qv.x);
                o[1] = f2b(hv.y * pv.y + qv.y);
                o[2] = f2b(hv.z * pv.z + qv.z);
                o[3] = f2b(hv.w * pv.w + qv.w);
                *(uint2*)(As + row * BK + q) = *(uint2*)o;
            }
        } else {
            stage_tile<128>(Ag + k0, K, As, tid);
        }
        stage_tile<BN>(Bg + k0, K, Bs, tid);
        __syncthreads();  // compiler drains vmcnt/lgkmcnt before barrier
#pragma unroll
        for (int ks = 0; ks < 2; ++ks) {
            int koff = ks * 32 + (lane >> 4) * 8;
            bf16x8 af[4], bfr[NJ];
#pragma unroll
            for (int i = 0; i < 4; ++i) {
                U4 t;
                t.u = *(const uint4*)(As + (wm + i * 16 + (lane & 15)) * BK + koff);
                af[i] = t.b;
            }
#pragma unroll
            for (int j = 0; j < NJ; ++j) {
                U4 t;
                t.u = *(const uint4*)(Bs + (wn + j * 16 + (lane & 15)) * BK + koff);
                bfr[j] = t.b;
            }
#pragma unroll
            for (int i = 0; i < 4; ++i)
#pragma unroll
                for (int j = 0; j < NJ; ++j)
                    acc[i][j] = __builtin_amdgcn_mfma_f32_16x16x32_bf16(af[i], bfr[j], acc[i][j], 0, 0, 0);
        }
    }

    // epilogue: D layout row=(lane>>4)*4+r, col=lane&15 (m91-verified)
#pragma unroll
    for (int i = 0; i < 4; ++i) {
        int row0 = bm + wm + i * 16 + (lane >> 4) * 4;
#pragma unroll
        for (int j = 0; j < NJ; ++j) {
            int col = bn + wn + j * 16 + (lane & 15);
            float bv = bias[col];
            if constexpr (FUSE) {
                float pv = p[col], qv = q0[col], av = a2[col], cv = c2[col];
#pragma unroll
                for (int r = 0; r < 4; ++r) {
                    int row = row0 + r;
                    float hv = h[(size_t)row * DIM + col];
                    float x1v = hv * pv + qv;
                    Cf[(size_t)row * Nn + col] = (x1v + acc[i][j][r] + bv) * av + cv;
                }
            } else {
#pragma unroll
                for (int r = 0; r < 4; ++r) {
                    float v = acc[i][j][r] + bv;
                    if (RELU) v = fmaxf(v, 0.f);
                    Cb[(size_t)(row0 + r) * Nn + col] = f2b(v);
                }
            }
        }
    }
}

// ---------------------------------------------------------------------------
extern "C" void kernel_launch(void* const* d_in, const int* in_sizes, int n_in,
                              void* d_out, int out_size, void* d_ws, size_t ws_size,
                              hipStream_t stream) {
    // inputs (all fp32): 0:A 1:h 2:qw 3:qb 4:kw 5:kb 6:vw 7:vb 8:ow 9:ob
    // 10:f1w 11:f1b 12:f2w 13:f2b 14-17:bn1 g,b,m,v 18-21:bn2 g,b,m,v
    const float* h = (const float*)d_in[1];
    const float* vw = (const float*)d_in[6];
    const float* vb = (const float*)d_in[7];
    const float* ow = (const float*)d_in[8];
    const float* ob = (const float*)d_in[9];
    const float* f1w = (const float*)d_in[10];
    const float* f1b = (const float*)d_in[11];
    const float* f2w = (const float*)d_in[12];
    const float* f2b = (const float*)d_in[13];
    const float* g1 = (const float*)d_in[14];
    const float* b1 = (const float*)d_in[15];
    const float* m1 = (const float*)d_in[16];
    const float* v1 = (const float*)d_in[17];
    const float* g2 = (const float*)d_in[18];
    const float* b2 = (const float*)d_in[19];
    const float* m2 = (const float*)d_in[20];
    const float* v2 = (const float*)d_in[21];
    float* out = (float*)d_out;

    char* ws = (char*)d_ws;
    float* hs = (float*)(ws + 0);              // 512 f32
    float* pC = (float*)(ws + 2048);           // 512 f32
    float* q0C = (float*)(ws + 4096);          // 512 f32
    float* a2C = (float*)(ws + 6144);          // 512 f32
    float* c2C = (float*)(ws + 8192);          // 512 f32
    ushort_t* Z = (ushort_t*)(ws + 16384);     // 8192*1024 bf16 (16 MB)
    ushort_t* W1T = Z + (size_t)NROWS * HID;   // 1024*512 bf16 (1 MB)
    ushort_t* W2T = W1T + (size_t)HID * DIM;   // 512*1024 bf16 (1 MB)

    hipMemsetAsync(hs, 0, 512 * sizeof(float), stream);
    colsum_kernel<<<256, 256, 0, stream>>>(h, hs);
    chainprep_kernel<<<16, 256, 0, stream>>>(hs, vw, vb, ow, ob,
                                             g1, b1, m1, v1, g2, b2, m2, v2,
                                             pC, q0C, a2C, c2C);
    transpose_both_kernel<<<1024, 256, 0, stream>>>(f1w, W1T, f2w, W2T);
    // GEMM1: Z = relu(bf16(h*p+q0) @ W1 + b1)  (x1 fused into A-staging)
    gemm_kernel<4, true, false, true><<<dim3(8, 64), 256, 0, stream>>>(
        nullptr, h, W1T, f1b, Z, nullptr, NROWS, HID, DIM,
        nullptr, pC, q0C, nullptr, nullptr);
    // GEMM2: out = ((h*p+q0) + Z @ W2 + b2)*a2 + c2  (final fused)
    gemm_kernel<2, false, true, false><<<dim3(8, 64), 256, 0, stream>>>(
        Z, nullptr, W2T, f2b, nullptr, out, NROWS, DIM, HID,
        h, pC, q0C, a2C, c2C);
}

// Round 3
// 427.729 us; speedup vs baseline: 1.0761x; 1.0761x over previous
//
#include <hip/hip_runtime.h>

#define NROWS 8192
#define DIM 512
#define HID 1024
#define BN_EPS 1e-5f

typedef unsigned short ushort_t;
typedef __attribute__((ext_vector_type(8))) __bf16 bf16x8;
typedef __attribute__((ext_vector_type(4))) float f32x4;

union U4 {
    uint4 u;
    bf16x8 b;
    ushort_t s[8];
};

static __device__ __forceinline__ ushort_t f2b(float f) {
    union { float f; unsigned int i; } c;
    c.f = f;
    unsigned int i = c.i;
    unsigned int r = (i + 0x7FFFu + ((i >> 16) & 1u)) >> 16;
    return (ushort_t)r;
}

// async global->LDS, 16B per lane. LDS dest is wave-uniform base + lane*16.
static __device__ __forceinline__ void gload_lds16(const ushort_t* g, ushort_t* l) {
    __builtin_amdgcn_global_load_lds((const __attribute__((address_space(1))) void*)g,
                                     (__attribute__((address_space(3))) void*)l, 16, 0, 0);
}

// ---------------------------------------------------------------------------
// 1) column-sum of h: hs[d] = sum_n h[n,d]   (hs pre-zeroed by memset)
// grid 256 x 256; each block covers 32 rows; LDS pre-reduce halves atomics.
__global__ void colsum_kernel(const float* __restrict__ h, float* __restrict__ hs) {
    __shared__ float red[512];
    int t = threadIdx.x;
    int col0 = (t & 127) * 4;
    int rsub = t >> 7;
    int row0 = blockIdx.x * 32;
    float acc[4] = {0.f, 0.f, 0.f, 0.f};
#pragma unroll
    for (int r = 0; r < 16; ++r) {
        int row = row0 + r * 2 + rsub;
        float4 v = *(const float4*)(h + (size_t)row * DIM + col0);
        acc[0] += v.x; acc[1] += v.y; acc[2] += v.z; acc[3] += v.w;
    }
    if (rsub) {
#pragma unroll
        for (int j = 0; j < 4; ++j) red[col0 + j] = acc[j];
    }
    __syncthreads();
    if (!rsub) {
#pragma unroll
        for (int j = 0; j < 4; ++j) atomicAdd(&hs[col0 + j], acc[j] + red[col0 + j]);
    }
}

// ---------------------------------------------------------------------------
// 2) matvec: outv[col] = sum_k xin[k] * W[k*512+col] + scaleB * bvec[col]
// 16 blocks x 256 thr; each block reads only its 32 columns (64 KB of W).
__global__ void matvec_kernel(const float* __restrict__ xin, const float* __restrict__ W,
                              const float* __restrict__ bvec, float scaleB,
                              float* __restrict__ outv) {
    __shared__ float red[8][32];
    int t = threadIdx.x;
    int col = blockIdx.x * 32 + (t & 31);
    int ks = t >> 5;
    float s = 0.f;
    for (int ki = 0; ki < 64; ++ki) {
        int k = ks * 64 + ki;
        s += xin[k] * W[k * 512 + col];
    }
    red[ks][t & 31] = s;
    __syncthreads();
    if (ks == 0) {
        float tot = scaleB * bvec[col];
#pragma unroll
        for (int r = 0; r < 8; ++r) tot += red[r][t & 31];
        outv[col] = tot;
    }
}

// ---------------------------------------------------------------------------
// 3) matvec2 + per-column BN constants fused: this block owns its 32 columns,
// so it can emit p/q0/a2/c2 directly.  t = xin@ow + ob; p=a1; q0=t*a1+c1.
__global__ void matvec_prep_kernel(const float* __restrict__ xin, const float* __restrict__ W,
                                   const float* __restrict__ bvec,
                                   const float* g1, const float* b1,
                                   const float* m1, const float* v1,
                                   const float* g2, const float* b2,
                                   const float* m2, const float* v2,
                                   float* __restrict__ p, float* __restrict__ q0,
                                   float* __restrict__ a2v, float* __restrict__ c2v) {
    __shared__ float red[8][32];
    int t = threadIdx.x;
    int col = blockIdx.x * 32 + (t & 31);
    int ks = t >> 5;
    float s = 0.f;
    for (int ki = 0; ki < 64; ++ki) {
        int k = ks * 64 + ki;
        s += xin[k] * W[k * 512 + col];
    }
    red[ks][t & 31] = s;
    __syncthreads();
    if (ks == 0) {
        float tot = bvec[col];
#pragma unroll
        for (int r = 0; r < 8; ++r) tot += red[r][t & 31];
        float a1 = g1[col] * rsqrtf(v1[col] + BN_EPS);
        float c1 = b1[col] - m1[col] * a1;
        p[col] = a1;
        q0[col] = tot * a1 + c1;
        float a2 = g2[col] * rsqrtf(v2[col] + BN_EPS);
        a2v[col] = a2;
        c2v[col] = b2[col] - m2[col] * a2;
    }
}

// ---------------------------------------------------------------------------
// 4) misc: both weight transposes + X1 build, one launch (pure gap removal).
// blocks 0..511   : f1w [512][1024] -> W1T bf16 [1024][512]
// blocks 512..1023: f2w [1024][512] -> W2T bf16 [512][1024]
// blocks 1024..3071: X1[n,d] = bf16(h[n,d]*p[d] + q0[d]), 8 elems/thread.
__global__ void misc_kernel(const float* __restrict__ f1w, ushort_t* __restrict__ W1T,
                            const float* __restrict__ f2w, ushort_t* __restrict__ W2T,
                            const float* __restrict__ h, const float* __restrict__ p,
                            const float* __restrict__ q0, ushort_t* __restrict__ x1) {
    __shared__ float tile[32][33];
    int bid = blockIdx.x;
    if (bid >= 1024) {
        int idx = ((bid - 1024) * 256 + threadIdx.x) * 8;
        int d0 = idx & (DIM - 1);
        float4 h0 = *(const float4*)(h + idx);
        float4 h1 = *(const float4*)(h + idx + 4);
        U4 o;
        o.s[0] = f2b(h0.x * p[d0 + 0] + q0[d0 + 0]);
        o.s[1] = f2b(h0.y * p[d0 + 1] + q0[d0 + 1]);
        o.s[2] = f2b(h0.z * p[d0 + 2] + q0[d0 + 2]);
        o.s[3] = f2b(h0.w * p[d0 + 3] + q0[d0 + 3]);
        o.s[4] = f2b(h1.x * p[d0 + 4] + q0[d0 + 4]);
        o.s[5] = f2b(h1.y * p[d0 + 5] + q0[d0 + 5]);
        o.s[6] = f2b(h1.z * p[d0 + 6] + q0[d0 + 6]);
        o.s[7] = f2b(h1.w * p[d0 + 7] + q0[d0 + 7]);
        *(uint4*)(x1 + idx) = o.u;
        return;
    }
    const float* in;
    ushort_t* out;
    int R, C, bx, by;
    if (bid < 512) {
        in = f1w; out = W1T; R = 512; C = 1024;
        bx = (bid & 31) * 32; by = (bid >> 5) * 32;
    } else {
        int b = bid - 512;
        in = f2w; out = W2T; R = 1024; C = 512;
        bx = (b & 15) * 32; by = (b >> 4) * 32;
    }
    int tx = threadIdx.x & 31, ty = threadIdx.x >> 5;
#pragma unroll
    for (int i = 0; i < 32; i += 8)
        tile[ty + i][tx] = in[(by + ty + i) * C + bx + tx];
    __syncthreads();
#pragma unroll
    for (int i = 0; i < 32; i += 8)
        out[(bx + ty + i) * R + by + tx] = f2b(tile[tx][ty + i]);
}

// ---------------------------------------------------------------------------
// stage a [ROWS][64] bf16 tile from global (row stride ldg) into linear LDS
// via global_load_lds x16.  8 chunks of 16B per row; chunk c = it*256 + tid.
template <int ROWS>
static __device__ __forceinline__ void stage_tile(const ushort_t* __restrict__ g, int ldg,
                                                  ushort_t* lds, int tid) {
#pragma unroll
    for (int it = 0; it < (ROWS * 8) / 256; ++it) {
        int c = it * 256 + tid;
        int row = c >> 3;
        int kc = (c & 7) << 3;
        const ushort_t* gp = g + (size_t)row * ldg + kc;
        ushort_t* lp = lds + ((it * 256 + (tid & 192)) << 3);  // wave-uniform base
        gload_lds16(gp, lp);
    }
}

// ---------------------------------------------------------------------------
// 5) GEMM, m97 structure: 128 x (NJ*32) tile, BK=64, global_load_lds width 16,
// linear LDS, 4 waves (2 x 2), 16x16x32 bf16 MFMA, 4 x NJ frags per wave.
// FUSE=true: epilogue computes out = ((h*p+q0) + acc + bias)*a2 + c2, fp32.
template <int NJ, bool RELU, bool FUSE>
__global__ __launch_bounds__(256) void gemm_kernel(
    const ushort_t* __restrict__ A, const ushort_t* __restrict__ BT,
    const float* __restrict__ bias, ushort_t* __restrict__ Cb,
    float* __restrict__ Cf, int M, int Nn, int K,
    const float* __restrict__ h, const float* __restrict__ p,
    const float* __restrict__ q0, const float* __restrict__ a2,
    const float* __restrict__ c2) {
    constexpr int BN = NJ * 32;
    constexpr int BK = 64;
    __shared__ ushort_t As[128 * BK];
    __shared__ ushort_t Bs[BN * BK];
    int tid = threadIdx.x;
    int lane = tid & 63, w = tid >> 6;
    int wm = (w & 1) * 64, wn = (w >> 1) * (NJ * 16);
    int bm = blockIdx.y * 128, bn = blockIdx.x * BN;

    f32x4 acc[4][NJ] = {};

    const ushort_t* Ag = A + (size_t)bm * K;
    const ushort_t* Bg = BT + (size_t)bn * K;

    for (int k0 = 0; k0 < K; k0 += BK) {
        __syncthreads();
        stage_tile<128>(Ag + k0, K, As, tid);
        stage_tile<BN>(Bg + k0, K, Bs, tid);
        __syncthreads();  // compiler drains vmcnt/lgkmcnt before barrier
#pragma unroll
        for (int ks = 0; ks < 2; ++ks) {
            int koff = ks * 32 + (lane >> 4) * 8;
            bf16x8 af[4], bfr[NJ];
#pragma unroll
            for (int i = 0; i < 4; ++i) {
                U4 t;
                t.u = *(const uint4*)(As + (wm + i * 16 + (lane & 15)) * BK + koff);
                af[i] = t.b;
            }
#pragma unroll
            for (int j = 0; j < NJ; ++j) {
                U4 t;
                t.u = *(const uint4*)(Bs + (wn + j * 16 + (lane & 15)) * BK + koff);
                bfr[j] = t.b;
            }
#pragma unroll
            for (int i = 0; i < 4; ++i)
#pragma unroll
                for (int j = 0; j < NJ; ++j)
                    acc[i][j] = __builtin_amdgcn_mfma_f32_16x16x32_bf16(af[i], bfr[j], acc[i][j], 0, 0, 0);
        }
    }

    // epilogue: D layout row=(lane>>4)*4+r, col=lane&15 (m91-verified)
#pragma unroll
    for (int i = 0; i < 4; ++i) {
        int row0 = bm + wm + i * 16 + (lane >> 4) * 4;
#pragma unroll
        for (int j = 0; j < NJ; ++j) {
            int col = bn + wn + j * 16 + (lane & 15);
            float bv = bias[col];
            if constexpr (FUSE) {
                float pv = p[col], qv = q0[col], av = a2[col], cv = c2[col];
#pragma unroll
                for (int r = 0; r < 4; ++r) {
                    int row = row0 + r;
                    float hv = h[(size_t)row * DIM + col];
                    float x1v = hv * pv + qv;
                    Cf[(size_t)row * Nn + col] = (x1v + acc[i][j][r] + bv) * av + cv;
                }
            } else {
#pragma unroll
                for (int r = 0; r < 4; ++r) {
                    float v = acc[i][j][r] + bv;
                    if (RELU) v = fmaxf(v, 0.f);
                    Cb[(size_t)(row0 + r) * Nn + col] = f2b(v);
                }
            }
        }
    }
}

// ---------------------------------------------------------------------------
extern "C" void kernel_launch(void* const* d_in, const int* in_sizes, int n_in,
                              void* d_out, int out_size, void* d_ws, size_t ws_size,
                              hipStream_t stream) {
    // inputs (all fp32): 0:A 1:h 2:qw 3:qb 4:kw 5:kb 6:vw 7:vb 8:ow 9:ob
    // 10:f1w 11:f1b 12:f2w 13:f2b 14-17:bn1 g,b,m,v 18-21:bn2 g,b,m,v
    const float* h = (const float*)d_in[1];
    const float* vw = (const float*)d_in[6];
    const float* vb = (const float*)d_in[7];
    const float* ow = (const float*)d_in[8];
    const float* ob = (const float*)d_in[9];
    const float* f1w = (const float*)d_in[10];
    const float* f1b = (const float*)d_in[11];
    const float* f2w = (const float*)d_in[12];
    const float* f2b = (const float*)d_in[13];
    const float* g1 = (const float*)d_in[14];
    const float* b1 = (const float*)d_in[15];
    const float* m1 = (const float*)d_in[16];
    const float* v1 = (const float*)d_in[17];
    const float* g2 = (const float*)d_in[18];
    const float* b2 = (const float*)d_in[19];
    const float* m2 = (const float*)d_in[20];
    const float* v2 = (const float*)d_in[21];
    float* out = (float*)d_out;

    char* ws = (char*)d_ws;
    float* hs = (float*)(ws + 0);              // 512 f32
    float* pC = (float*)(ws + 2048);           // 512 f32
    float* q0C = (float*)(ws + 4096);          // 512 f32
    float* a2C = (float*)(ws + 6144);          // 512 f32
    float* c2C = (float*)(ws + 8192);          // 512 f32
    float* sBuf = (float*)(ws + 10240);        // 512 f32
    ushort_t* X1 = (ushort_t*)(ws + 16384);    // 8192*512 bf16 (8 MB)
    ushort_t* Z = X1 + (size_t)NROWS * DIM;    // 8192*1024 bf16 (16 MB)
    ushort_t* W1T = Z + (size_t)NROWS * HID;   // 1024*512 bf16 (1 MB)
    ushort_t* W2T = W1T + (size_t)HID * DIM;   // 512*1024 bf16 (1 MB)

    hipMemsetAsync(hs, 0, 512 * sizeof(float), stream);
    colsum_kernel<<<256, 256, 0, stream>>>(h, hs);
    matvec_kernel<<<16, 256, 0, stream>>>(hs, vw, vb, 8192.0f, sBuf);
    matvec_prep_kernel<<<16, 256, 0, stream>>>(sBuf, ow, ob, g1, b1, m1, v1,
                                               g2, b2, m2, v2, pC, q0C, a2C, c2C);
    misc_kernel<<<3072, 256, 0, stream>>>(f1w, W1T, f2w, W2T, h, pC, q0C, X1);
    // GEMM1: Z = relu(X1 @ W1 + b1)
    gemm_kernel<4, true, false><<<dim3(8, 64), 256, 0, stream>>>(
        X1, W1T, f1b, Z, nullptr, NROWS, HID, DIM,
        nullptr, nullptr, nullptr, nullptr, nullptr);
    // GEMM2: out = ((h*p+q0) + Z @ W2 + b2)*a2 + c2  (final fused)
    gemm_kernel<2, false, true><<<dim3(8, 64), 256, 0, stream>>>(
        Z, W2T, f2b, nullptr, out, NROWS, DIM, HID,
        h, pC, q0C, a2C, c2C);
}